// Round 2
// 69.458 us; speedup vs baseline: 1.0534x; 1.0534x over previous
//
#include <hip/hip_runtime.h>

// Problem constants (from reference setup_inputs)
constexpr int S_  = 16;
constexpr int B_  = 64;
constexpr int T_  = 640;
constexpr int D_  = 256;
constexpr int H_  = 64;          // distinct harmonics = D / NUM_CH
constexpr int SB_ = S_ * B_;     // 1024 independent (s,b) problems

__device__ __forceinline__ float fractf_(float x) { return __builtin_amdgcn_fractf(x); }
// sin(2*pi*r); r must already be in [0,1)
__device__ __forceinline__ float sin2pi_(float r) { return __builtin_amdgcn_sinf(r); }

// out[sb,d] = a_d*cos(phi_d) * S_h + a_d*sin(phi_d) * C_h,  h = d>>2
//   S_h = sum_k sin(2*pi*(mu*k - hp*q)) * x_k ; C_h analog with cos,
//   mu = hp*f/16000 mod 1, q = f*tau, hp = h+1.
// Single fused kernel: per-(s,b) fp64 exp recomputed per-thread (uniform),
// per-d phi decomposition folded into the epilogue.
// Inner loop: Chebyshev 3-term recurrence s_{k+1} = K*s_k - s_{k-1},
// K = 2*cos(2*pi*mu) -> 4 VALU/sample (2 acc FMA + 2 recurrence FMA),
// two interleaved 80-sample streams per lane for ILP; anchors fp64 mod 1.
__global__ __launch_bounds__(256, 4)
void sinenet_fused(const float* __restrict__ x,
                   const float* __restrict__ nlf,
                   const float* __restrict__ tau,
                   const float* __restrict__ a,
                   const float* __restrict__ phi,
                   float* __restrict__ out)
{
    __shared__ __align__(16) float xs[T_];
    __shared__ float redS[4][H_];
    __shared__ float redC[4][H_];

    const int sb   = blockIdx.x;
    const int tid  = threadIdx.x;
    const int w    = tid >> 6;       // wave id 0..3
    const int lane = tid & 63;       // harmonic h

    // stage x[sb,:] into LDS (160 float4)
    const float4* xg4 = reinterpret_cast<const float4*>(x + (size_t)sb * T_);
    if (tid < T_ / 4) reinterpret_cast<float4*>(xs)[tid] = xg4[tid];

    // epilogue coefficients: issue the (L2-resident) loads early
    const float av = a[tid];
    const float pv = phi[tid];

    // per-(s,b) scalars, fp64, computed redundantly (uniform inputs)
    const double fd = exp((double)nlf[sb] * 0.373288 + 5.02654);
    const double g  = fd * (1.0 / 16000.0);   // revs/sample at h=1
    const double q  = fd * (double)tau[sb];   // revs at h=1

    const int kA = w * 160;          // stream A start; stream B = kA + 80

    // per-lane phase anchors (exact mod-1 in fp64)
    const double hp = (double)(lane + 1);
    double mu = hp * g;                    mu -= floor(mu);
    double rA = mu * (double)kA - hp * q;  rA -= floor(rA);
    double rB = rA + mu * 80.0;            rB -= floor(rB);

    const float muf = (float)mu;
    const float sm  = sin2pi_(fractf_(muf));          // sin(step)
    const float cm  = sin2pi_(fractf_(muf + 0.25f));  // cos(step)
    const float K   = 2.0f * cm;                      // Chebyshev coefficient

    // current-sample values at kA / kB
    float sA1 = sin2pi_(fractf_((float)rA));
    float cA1 = sin2pi_(fractf_((float)rA + 0.25f));
    float sB1 = sin2pi_(fractf_((float)rB));
    float cB1 = sin2pi_(fractf_((float)rB + 0.25f));
    // previous-sample values via backward rotation by mu
    float sA0 = fmaf(sA1, cm, -(cA1 * sm));   // sin(rA - mu)
    float cA0 = fmaf(cA1, cm,   sA1 * sm);    // cos(rA - mu)
    float sB0 = fmaf(sB1, cm, -(cB1 * sm));
    float cB0 = fmaf(cB1, cm,   sB1 * sm);

    float SsA = 0.0f, CsA = 0.0f, SsB = 0.0f, CsB = 0.0f;

    __syncthreads();

    const float4* xa = reinterpret_cast<const float4*>(xs + kA);
    const float4* xb = xa + 20;   // xs + kA + 80

// consumes current (sc,cc), overwrites prev (sp,cp) with NEXT sample;
// roles alternate each step so no register moves are needed.
#define STEP2(sp, sc, cp, cc, Sa, Ca, xv)                 \
    Sa = fmaf(sc, xv, Sa); Ca = fmaf(cc, xv, Ca);         \
    sp = fmaf(K, sc, -sp); cp = fmaf(K, cc, -cp);

#pragma unroll 4
    for (int i = 0; i < 20; ++i) {
        const float4 va = xa[i];
        const float4 vb = xb[i];
        STEP2(sA0, sA1, cA0, cA1, SsA, CsA, va.x)  STEP2(sB0, sB1, cB0, cB1, SsB, CsB, vb.x)
        STEP2(sA1, sA0, cA1, cA0, SsA, CsA, va.y)  STEP2(sB1, sB0, cB1, cB0, SsB, CsB, vb.y)
        STEP2(sA0, sA1, cA0, cA1, SsA, CsA, va.z)  STEP2(sB0, sB1, cB0, cB1, SsB, CsB, vb.z)
        STEP2(sA1, sA0, cA1, cA0, SsA, CsA, va.w)  STEP2(sB1, sB0, cB1, cB0, SsB, CsB, vb.w)
    }
#undef STEP2

    redS[w][lane] = SsA + SsB;
    redC[w][lane] = CsA + CsB;

    // per-d phi decomposition (overlaps with the barrier wait)
    const float pr  = pv * 0.15915494309189535f;      // phi in revolutions
    const float sad = av * sin2pi_(fractf_(pr));      // a*sin(phi)
    const float cad = av * sin2pi_(fractf_(pr + 0.25f)); // a*cos(phi)

    __syncthreads();

    // epilogue: one output d per thread, coalesced
    const int h = tid >> 2;
    const float Sh = redS[0][h] + redS[1][h] + redS[2][h] + redS[3][h];
    const float Ch = redC[0][h] + redC[1][h] + redC[2][h] + redC[3][h];
    out[(size_t)sb * D_ + tid] = fmaf(cad, Sh, sad * Ch);
}

extern "C" void kernel_launch(void* const* d_in, const int* in_sizes, int n_in,
                              void* d_out, int out_size, void* d_ws, size_t ws_size,
                              hipStream_t stream)
{
    hipLaunchKernelGGL(sinenet_fused, dim3(SB_), dim3(256), 0, stream,
                       (const float*)d_in[0], (const float*)d_in[1],
                       (const float*)d_in[2], (const float*)d_in[3],
                       (const float*)d_in[4], (float*)d_out);
}

// Round 3
// 68.808 us; speedup vs baseline: 1.0634x; 1.0095x over previous
//
#include <hip/hip_runtime.h>

// Problem constants (from reference setup_inputs)
constexpr int S_  = 16;
constexpr int B_  = 64;
constexpr int T_  = 640;
constexpr int D_  = 256;
constexpr int H_  = 64;          // distinct harmonics = D / NUM_CH
constexpr int SB_ = S_ * B_;     // 1024 independent (s,b) problems

typedef float v2f __attribute__((ext_vector_type(2)));

__device__ __forceinline__ float fractf_(float x) { return __builtin_amdgcn_fractf(x); }
// sin(2*pi*r); r must already be in [0,1)
__device__ __forceinline__ float sin2pi_(float r) { return __builtin_amdgcn_sinf(r); }
__device__ __forceinline__ v2f   fma2_(v2f a, v2f b, v2f c) { return __builtin_elementwise_fma(a, b, c); }

// out[sb,d] = a_d*cos(phi_d) * S_h + a_d*sin(phi_d) * C_h,  h = d>>2
//   S_h = sum_k sin(2*pi*(mu*k - hp*q)) * x_k ; C_h analog with cos,
//   mu = hp*f/16000 mod 1, q = f*tau, hp = h+1.
// Single fused kernel. Inner loop: Chebyshev 3-term recurrence
// s_{k+1} = K*s_k - s_{k-1}, K = 2*cos(2*pi*mu), with the two 80-sample
// streams of each wave PACKED into float2 lanes (same harmonic -> same K)
// so every op is one v_pk_fma_f32: 2 packed acc-FMA + 2 packed rec-FMA
// per k-step = 2 VALU inst/sample. x staged in LDS pre-interleaved as
// (x[k], x[k+80]) pairs so one uniform ds_read feeds both halves
// (same-address broadcast, conflict-free). Anchors fp64 mod 1.
__global__ __launch_bounds__(256, 4)
void sinenet_fused(const float* __restrict__ x,
                   const float* __restrict__ nlf,
                   const float* __restrict__ tau,
                   const float* __restrict__ a,
                   const float* __restrict__ phi,
                   float* __restrict__ out)
{
    __shared__ __align__(16) v2f xi[4][80];   // per-wave interleaved pairs
    __shared__ float redS[4][H_];
    __shared__ float redC[4][H_];

    const int sb   = blockIdx.x;
    const int tid  = threadIdx.x;
    const int w    = tid >> 6;       // wave id 0..3
    const int lane = tid & 63;       // harmonic h

    // stage x[sb,:] into LDS, interleaved: xi[w][j] = (x[w*160+j], x[w*160+80+j])
    if (tid < T_ / 4) {
        const float4 p = reinterpret_cast<const float4*>(x + (size_t)sb * T_)[tid];
        const int k0 = tid * 4;          // first sample of this float4
        const int ww = k0 / 160;         // owning wave segment
        const int j  = k0 - ww * 160;    // offset within segment (float4 never straddles 80)
        if (j < 80) {
            xi[ww][j+0].x = p.x; xi[ww][j+1].x = p.y;
            xi[ww][j+2].x = p.z; xi[ww][j+3].x = p.w;
        } else {
            const int jj = j - 80;
            xi[ww][jj+0].y = p.x; xi[ww][jj+1].y = p.y;
            xi[ww][jj+2].y = p.z; xi[ww][jj+3].y = p.w;
        }
    }

    // epilogue coefficients: issue the (L2-resident) loads early
    const float av = a[tid];
    const float pv = phi[tid];

    // per-(s,b) scalars, fp64, computed redundantly (uniform inputs)
    const double fd = exp((double)nlf[sb] * 0.373288 + 5.02654);
    const double g  = fd * (1.0 / 16000.0);   // revs/sample at h=1
    const double q  = fd * (double)tau[sb];   // revs at h=1

    const int kA = w * 160;          // stream A start; stream B = kA + 80

    // per-lane phase anchors (exact mod-1 in fp64)
    const double hp = (double)(lane + 1);
    double mu = hp * g;                    mu -= floor(mu);
    double rA = mu * (double)kA - hp * q;  rA -= floor(rA);
    double rB = rA + mu * 80.0;            rB -= floor(rB);

    const float muf = (float)mu;
    const float sm  = sin2pi_(fractf_(muf));          // sin(step)
    const float cm  = sin2pi_(fractf_(muf + 0.25f));  // cos(step)
    const v2f   K2  = { 2.0f * cm, 2.0f * cm };       // Chebyshev coefficient
    const v2f   sm2 = { sm, sm };
    const v2f   cm2 = { cm, cm };

    // current-sample values, packed (streamA, streamB)
    v2f s1 = { sin2pi_(fractf_((float)rA)),          sin2pi_(fractf_((float)rB)) };
    v2f c1 = { sin2pi_(fractf_((float)rA + 0.25f)),  sin2pi_(fractf_((float)rB + 0.25f)) };
    // previous-sample values via backward rotation by mu
    v2f s0 = fma2_(s1, cm2, -(c1 * sm2));   // sin(r - mu)
    v2f c0 = fma2_(c1, cm2,   s1 * sm2);    // cos(r - mu)

    v2f S2 = { 0.0f, 0.0f };
    v2f C2 = { 0.0f, 0.0f };

    __syncthreads();

    const v2f* xw = xi[w];

// consumes current (sc,cc), overwrites prev (sp,cp) with NEXT sample;
// roles alternate each step so no register moves are needed.
#define STEP2(sp, sc, cp, cc, xv)                         \
    S2 = fma2_(sc, xv, S2); C2 = fma2_(cc, xv, C2);       \
    sp = fma2_(K2, sc, -sp); cp = fma2_(K2, cc, -cp);

#pragma unroll 4
    for (int i = 0; i < 20; ++i) {
        const v2f p0 = xw[4*i+0];
        const v2f p1 = xw[4*i+1];
        const v2f p2 = xw[4*i+2];
        const v2f p3 = xw[4*i+3];
        STEP2(s0, s1, c0, c1, p0)
        STEP2(s1, s0, c1, c0, p1)
        STEP2(s0, s1, c0, c1, p2)
        STEP2(s1, s0, c1, c0, p3)
    }
#undef STEP2

    redS[w][lane] = S2.x + S2.y;
    redC[w][lane] = C2.x + C2.y;

    // per-d phi decomposition (overlaps with the barrier wait)
    const float pr  = pv * 0.15915494309189535f;         // phi in revolutions
    const float sad = av * sin2pi_(fractf_(pr));         // a*sin(phi)
    const float cad = av * sin2pi_(fractf_(pr + 0.25f)); // a*cos(phi)

    __syncthreads();

    // epilogue: one output d per thread, coalesced
    const int h = tid >> 2;
    const float Sh = redS[0][h] + redS[1][h] + redS[2][h] + redS[3][h];
    const float Ch = redC[0][h] + redC[1][h] + redC[2][h] + redC[3][h];
    out[(size_t)sb * D_ + tid] = fmaf(cad, Sh, sad * Ch);
}

extern "C" void kernel_launch(void* const* d_in, const int* in_sizes, int n_in,
                              void* d_out, int out_size, void* d_ws, size_t ws_size,
                              hipStream_t stream)
{
    hipLaunchKernelGGL(sinenet_fused, dim3(SB_), dim3(256), 0, stream,
                       (const float*)d_in[0], (const float*)d_in[1],
                       (const float*)d_in[2], (const float*)d_in[3],
                       (const float*)d_in[4], (float*)d_out);
}